// Round 9
// baseline (113.640 us; speedup 1.0000x reference)
//
#include <hip/hip_runtime.h>
#include <hip/hip_bf16.h>

typedef short bf16x8 __attribute__((ext_vector_type(8)));
typedef float f32x4 __attribute__((ext_vector_type(4)));
typedef long l64x2 __attribute__((ext_vector_type(2)));
typedef unsigned short u16;
typedef unsigned char u8;

#define NB2 (-0.35f * 1.44269504088896340736f)
#define MFP8(a,b,c) __builtin_amdgcn_mfma_f32_16x16x32_fp8_fp8(a, b, c, 0, 0, 0)
#define MFBF(a,b,c) __builtin_amdgcn_mfma_f32_16x16x32_bf16(a, b, c, 0, 0, 0)

__device__ __forceinline__ u16 f2bf(float f) {
  union { float f; unsigned int u; } v; v.f = f;
  unsigned int x = v.u;
  return (u16)((x + 0x7FFFu + ((x >> 16) & 1u)) >> 16);
}

__device__ __forceinline__ u8 f2e4m3(float f) {
  unsigned int u = __float_as_uint(f);
  u8 s = (u8)((u >> 24) & 0x80u);
  float a = fabsf(f);
  if (a >= 448.f) return s | 0x7E;
  if (a < 0.015625f) return s | (u8)(int)rintf(a * 512.f);
  unsigned int m = u & 0x7fffffffu;
  unsigned int r = m + 0x7FFFFu + ((m >> 20) & 1u);
  return s | (u8)((((r >> 23) - 120u) << 3) | ((r >> 20) & 7u));
}

__device__ __forceinline__ unsigned int pk4(float a, float b, float c, float d) {
#if __has_builtin(__builtin_amdgcn_cvt_pk_fp8_f32)
  int v = __builtin_amdgcn_cvt_pk_fp8_f32(a, b, 0, false);
  v = __builtin_amdgcn_cvt_pk_fp8_f32(c, d, v, true);
  return (unsigned int)v;
#else
  return (unsigned int)f2e4m3(a) | ((unsigned int)f2e4m3(b) << 8)
       | ((unsigned int)f2e4m3(c) << 16) | ((unsigned int)f2e4m3(d) << 24);
#endif
}

#define GLOAD_LDS(g, l) __builtin_amdgcn_global_load_lds( \
    (const __attribute__((address_space(1))) unsigned int*)(g), \
    (__attribute__((address_space(3))) unsigned int*)(l), 16, 0, 0)

// ---------- prep: x fp32 rows -> fp8 rows + row sum-of-squares ----------
__global__ __launch_bounds__(512)
void prep_x8(const float* __restrict__ src, u8* __restrict__ dst,
             float* __restrict__ sq) {
  const int row = blockIdx.x * 8 + (threadIdx.x >> 6);
  const int lane = threadIdx.x & 63;
  const float4* p = (const float4*)(src + (size_t)row * 512) + lane * 2;
  float4 a = p[0], b = p[1];
  float ss = a.x*a.x + a.y*a.y + a.z*a.z + a.w*a.w
           + b.x*b.x + b.y*b.y + b.z*b.z + b.w*b.w;
  uint2 o;
  o.x = pk4(a.x, a.y, a.z, a.w);
  o.y = pk4(b.x, b.y, b.z, b.w);
  ((uint2*)(dst + (size_t)row * 512))[lane] = o;
  ss += __shfl_xor(ss, 1);  ss += __shfl_xor(ss, 2);
  ss += __shfl_xor(ss, 4);  ss += __shfl_xor(ss, 8);
  ss += __shfl_xor(ss, 16); ss += __shfl_xor(ss, 32);
  if (lane == 0) sq[row] = ss;
}

// ---------- prep: centers -> fp8 frag-stream in 32-center chunks + csq ----------
// chunk = c>>5; within: [sl(4)][32c][128B]; unit u = (lg*2 + (s>>1)) ^ (c&7);
// element k = sl*128 + s*32 + lg*8, stored at u*16 + (s&1)*8.
__global__ __launch_bounds__(256)
void prep_cen(const float* __restrict__ cen, u8* __restrict__ cfr,
              float* __restrict__ csq) {
  const int t = threadIdx.x;
  const int c = blockIdx.x * 4 + (t >> 6);
  const int i6 = t & 63;                  // sl*16 + s*4 + lg
  const int sl = i6 >> 4, s = (i6 >> 2) & 3, lg = i6 & 3;
  const float* p = cen + (size_t)c * 512 + i6 * 8;
  float4 a = *(const float4*)p, b = *(const float4*)(p + 4);
  float ss = a.x*a.x + a.y*a.y + a.z*a.z + a.w*a.w
           + b.x*b.x + b.y*b.y + b.z*b.z + b.w*b.w;
  uint2 o;
  o.x = pk4(a.x, a.y, a.z, a.w);
  o.y = pk4(b.x, b.y, b.z, b.w);
  const int u = (lg * 2 + (s >> 1)) ^ (c & 7);
  *(uint2*)(cfr + (size_t)(c >> 5) * 16384 + sl * 4096 + (c & 31) * 128
            + u * 16 + (s & 1) * 8) = o;
  ss += __shfl_xor(ss, 1);  ss += __shfl_xor(ss, 2);
  ss += __shfl_xor(ss, 4);  ss += __shfl_xor(ss, 8);
  ss += __shfl_xor(ss, 16); ss += __shfl_xor(ss, 32);
  if (i6 == 0) csq[c] = ss;
}

// ---------- prep: W [4096][128] f32 -> chunk-major bf16 [chunk(128)][o(128)][32c swz] ----------
// element (o,c): byte = (c>>5)*8192 + o*64 + (((c&31)>>3 ^ (o&3))*16) + (c&7)*2
__global__ __launch_bounds__(256)
void prep_w(const float* __restrict__ W, u8* __restrict__ wt) {
  __shared__ u16 t_[128 * 66];
  const int c0 = blockIdx.x * 64;
  const int t = threadIdx.x;
#pragma unroll
  for (int it = 0; it < 32; ++it) {
    int idx = it * 256 + t;
    int cl = idx >> 7;
    int o  = idx & 127;
    t_[o * 66 + cl] = f2bf(W[(size_t)(c0 + cl) * 128 + o]);
  }
  __syncthreads();
#pragma unroll
  for (int it = 0; it < 4; ++it) {
    int idx = it * 256 + t;            // 0..1023 : 16B units
    int o  = idx >> 3;
    int uu = idx & 7;
    int ch = uu >> 2;                  // local chunk 0/1
    int g  = uu & 3;                   // c-granule of 8
    int u  = g ^ (o & 3);
    u16* d = (u16*)(wt + ((size_t)(c0 >> 5) + ch) * 8192 + o * 64 + u * 16);
    const u16* s_ = &t_[o * 66 + ch * 32 + g * 8];
#pragma unroll
    for (int j = 0; j < 8; ++j) d[j] = s_[j];
  }
}

// ---------- init: out = bias ----------
__global__ __launch_bounds__(256)
void init_out(const float* __restrict__ bias, float* __restrict__ out) {
  const int i4 = blockIdx.x * 256 + threadIdx.x;
  float4 b = ((const float4*)bias)[i4 & 31];
  ((float4*)out)[i4] = b;
}

// ---------- main: 512 blocks = 128 row-tiles(128) x 4 quarters(1024c); 2 blocks/CU ----------
__global__ __launch_bounds__(512, 4)
void rbf_main(const u8* __restrict__ xq8, const u8* __restrict__ cfr,
              const u8* __restrict__ wtgb, const float* __restrict__ csq_g,
              const float* __restrict__ xsq_g, float* __restrict__ out)
{
  __shared__ __align__(16) u8  cs[2][16384];   // center chunk dbuf (32c x 512k fp8)
  __shared__ __align__(16) u8  wt[2][8192];    // W chunk dbuf [128o][32c] bf16 swz
  __shared__ __align__(16) u16 pl[4096];       // P tile [128m][32c] (wave-private rows)
  __shared__ __align__(16) float csq_l[1024];
  __shared__ __align__(16) float xsq_l[128];

  const int tid = threadIdx.x;
  const int lane = tid & 63;
  const int mw = tid >> 6;                 // wave 0..7 -> rows mw*16..+16
  const int l15 = lane & 15;
  const int lg = lane >> 4;
  const int bid = blockIdx.x;
  const int chq = bid & 3;                 // center quarter
  const size_t r0 = (size_t)(bid >> 2) * 128;

#define S_CS(cc) do { \
    const u8* sG_ = cfr + ((size_t)(chq * 32 + (cc)) << 14) + tid * 16; \
    u8* sL_ = &cs[(cc) & 1][0] + tid * 16; \
    GLOAD_LDS(sG_,        sL_); \
    GLOAD_LDS(sG_ + 8192, sL_ + 8192); \
  } while (0)

#define S_W(cc) do { \
    GLOAD_LDS(wtgb + ((size_t)(chq * 32 + (cc)) << 13) + tid * 16, \
              &wt[(cc) & 1][0] + tid * 16); \
  } while (0)

  // prologue staging
  if (tid < 32)  GLOAD_LDS(xsq_g + r0 + tid * 4, xsq_l + tid * 4);
  if (tid < 256) GLOAD_LDS(csq_g + chq * 1024 + tid * 4, csq_l + tid * 4);
  S_CS(0);
  S_W(0);

  // x fragments (fp8) -> registers: 16 rows/wave
  long xf[16];
  {
    const u8* xr = xq8 + (r0 + mw * 16 + l15) * 512 + lg * 8;
#pragma unroll
    for (int ks = 0; ks < 16; ++ks)
      xf[ks] = *(const long*)(xr + ks * 32);
  }

  asm volatile("s_waitcnt vmcnt(0)" ::: "memory");
  __builtin_amdgcn_s_barrier();
  __builtin_amdgcn_sched_barrier(0);

  float xq[4], cq[2];
#pragma unroll
  for (int r = 0; r < 4; ++r) xq[r] = xsq_l[mw * 16 + lg * 4 + r];
#pragma unroll
  for (int ct = 0; ct < 2; ++ct) cq[ct] = csq_l[ct * 16 + l15];

  // LDS byte-offset bases
  const int cbase  = l15 * 128 + (((lg * 2) ^ (l15 & 7)) << 4);          // GEMM1 B (per slot)
  const int pabase = (mw * 16 + l15) * 64
                   + ((lg ^ (l15 & 3) ^ (l15 >> 2)) << 4);               // P A-frag
  const int wbase  = l15 * 64 + ((lg ^ (l15 & 3)) << 4);                 // W B-frag (ot stride 1024)

  const f32x4 z4 = {0.f, 0.f, 0.f, 0.f};
  f32x4 sacc[2] = {z4, z4};
  f32x4 oa[8] = {z4, z4, z4, z4, z4, z4, z4, z4};

#pragma unroll 1
  for (int cc = 0; cc < 32; ++cc) {
    if (cc < 31) { S_CS(cc + 1); S_W(cc + 1); }
    const u8* csb = &cs[cc & 1][0];

    // ---- GEMM1: 16 rows x 32 centers x K=512 ----
#pragma unroll
    for (int sl = 0; sl < 4; ++sl) {
      l64x2 B00 = *(const l64x2*)(csb + sl * 4096 + cbase);           // ct0, s0/s1
      l64x2 B01 = *(const l64x2*)(csb + sl * 4096 + (cbase ^ 16));    // ct0, s2/s3
      l64x2 B10 = *(const l64x2*)(csb + sl * 4096 + 2048 + cbase);    // ct1, s0/s1
      l64x2 B11 = *(const l64x2*)(csb + sl * 4096 + 2048 + (cbase ^ 16));
      __builtin_amdgcn_s_setprio(1);
      sacc[0] = MFP8(xf[sl * 4 + 0], B00[0], sacc[0]);
      sacc[1] = MFP8(xf[sl * 4 + 0], B10[0], sacc[1]);
      sacc[0] = MFP8(xf[sl * 4 + 1], B00[1], sacc[0]);
      sacc[1] = MFP8(xf[sl * 4 + 1], B10[1], sacc[1]);
      sacc[0] = MFP8(xf[sl * 4 + 2], B01[0], sacc[0]);
      sacc[1] = MFP8(xf[sl * 4 + 2], B11[0], sacc[1]);
      sacc[0] = MFP8(xf[sl * 4 + 3], B01[1], sacc[0]);
      sacc[1] = MFP8(xf[sl * 4 + 3], B11[1], sacc[1]);
      __builtin_amdgcn_s_setprio(0);
    }

    // ---- rbf -> pl (wave-private rows; swz spreads rows across units) ----
#pragma unroll
    for (int ct = 0; ct < 2; ++ct) {
#pragma unroll
      for (int r = 0; r < 4; ++r) {
        const int m = mw * 16 + lg * 4 + r;
        float v = __builtin_amdgcn_exp2f(NB2 * (xq[r] + cq[ct] - 2.f * sacc[ct][r]));
        pl[m * 32 + (((ct * 2 + (l15 >> 3)) ^ r ^ lg) * 8) + (l15 & 7)] = f2bf(v);
      }
      sacc[ct] = z4;
    }
    asm volatile("s_waitcnt lgkmcnt(0)" ::: "memory");
    __builtin_amdgcn_sched_barrier(0);

    // ---- GEMM2: P(16x32) x W(32x128) ----
    {
      const u8* plb = (const u8*)pl;
      const u8* wtb = &wt[cc & 1][0];
      bf16x8 pa = *(const bf16x8*)(plb + pabase);
      bf16x8 w0 = *(const bf16x8*)(wtb + wbase);
      bf16x8 w1 = *(const bf16x8*)(wtb + wbase + 1024);
      bf16x8 w2 = *(const bf16x8*)(wtb + wbase + 2048);
      bf16x8 w3 = *(const bf16x8*)(wtb + wbase + 3072);
      __builtin_amdgcn_s_setprio(1);
      oa[0] = MFBF(pa, w0, oa[0]);
      oa[1] = MFBF(pa, w1, oa[1]);
      oa[2] = MFBF(pa, w2, oa[2]);
      oa[3] = MFBF(pa, w3, oa[3]);
      __builtin_amdgcn_s_setprio(0);
      bf16x8 w4 = *(const bf16x8*)(wtb + wbase + 4096);
      bf16x8 w5 = *(const bf16x8*)(wtb + wbase + 5120);
      bf16x8 w6 = *(const bf16x8*)(wtb + wbase + 6144);
      bf16x8 w7 = *(const bf16x8*)(wtb + wbase + 7168);
      __builtin_amdgcn_s_setprio(1);
      oa[4] = MFBF(pa, w4, oa[4]);
      oa[5] = MFBF(pa, w5, oa[5]);
      oa[6] = MFBF(pa, w6, oa[6]);
      oa[7] = MFBF(pa, w7, oa[7]);
      __builtin_amdgcn_s_setprio(0);
    }

    const int ncc = (cc < 31) ? cc + 1 : 31;
#pragma unroll
    for (int ct = 0; ct < 2; ++ct) cq[ct] = csq_l[ncc * 32 + ct * 16 + l15];

    asm volatile("s_waitcnt vmcnt(0)" ::: "memory");
    __builtin_amdgcn_s_barrier();
    __builtin_amdgcn_sched_barrier(0);
  }

  // epilogue: out += partial (bias added by init_out)
#pragma unroll
  for (int ot = 0; ot < 8; ++ot) {
    const int o = ot * 16 + l15;
#pragma unroll
    for (int r = 0; r < 4; ++r) {
      const int m = mw * 16 + lg * 4 + r;
      atomicAdd(&out[(r0 + m) * 128 + o], oa[ot][r]);
    }
  }
#undef S_CS
#undef S_W
}

extern "C" void kernel_launch(void* const* d_in, const int* in_sizes, int n_in,
                              void* d_out, int out_size, void* d_ws, size_t ws_size,
                              hipStream_t stream) {
  (void)in_sizes; (void)n_in; (void)out_size; (void)ws_size;
  const float* x   = (const float*)d_in[0];
  const float* cen = (const float*)d_in[1];
  const float* W   = (const float*)d_in[2];
  const float* b   = (const float*)d_in[3];
  u8* xq8 = (u8*)d_ws;                          // 16384*512 = 8 MB
  u8* cfr = xq8 + (size_t)16384 * 512;          // 4096*512  = 2 MB (frag stream)
  u8* wtgb = cfr + (size_t)4096 * 512;          // 128*4096 bf16 = 1 MB (chunk-major)
  float* csq = (float*)(wtgb + (size_t)128 * 4096 * 2);  // 16 KB
  float* xsq = csq + 4096;                      // 64 KB
  prep_x8<<<2048, 512, 0, stream>>>(x, xq8, xsq);
  prep_cen<<<1024, 256, 0, stream>>>(cen, cfr, csq);
  prep_w<<<64, 256, 0, stream>>>(W, wtgb);
  init_out<<<2048, 256, 0, stream>>>(b, (float*)d_out);
  rbf_main<<<512, 512, 0, stream>>>(xq8, cfr, wtgb, csq, xsq, (float*)d_out);
}